// Round 18
// baseline (659.147 us; speedup 1.0000x reference)
//
#include <hip/hip_runtime.h>

#define DZ 64
#define DX 32
#define DS 16
#define TT 1024
#define NS 1024
#define SNZ (NS * DZ)
#define SNX (NS * DX)
#define SU4 (NS * DS / 4)     // per-step stride in float4 units (u)

// ---- LDS layout (floats) ----
// staging (read once into registers):
#define AW_B 0
#define C_B  (AW_B + DZ * (DZ + 1))
#define B_B  (C_B + DZ * (DS + 1))
#define SMEM_FLOATS (B_B + DX * (DZ + 1))   // 7328 floats = 29.3 KB
// runtime overlay ALIASES the staging region (anti-remat clobber, R8-proven):
#define ZR_O 0                 // raw z_t   [sim2][64]
#define RZ_O 128               // relu z_t  [sim2][64]
#define PM_O 256               // mu partials [par2][sim2][kh2][64]
#define PX_O 768               // x partials  [par2][sim2][32]   (ends 896)

__device__ __forceinline__ float softplus_eps(float x) {
    // jax.nn.softplus = max(x,0) + log1p(exp(-|x|)); +1e-6
    return fmaxf(x, 0.f) + log1pf(expf(-fabsf(x))) + 1e-6f;
}

// LDS-only barrier (R16-proven): orders the partial exchange without
// draining in-flight global prefetch loads.
__device__ __forceinline__ void lds_barrier() {
    asm volatile("s_waitcnt lgkmcnt(0)" ::: "memory");
    __builtin_amdgcn_s_barrier();
}

// 2 sims per wave (ILP) x 2 waves per sim (k-split). 512 blocks x 128 thr
// = 1024 waves (1/SIMD). Weights (59 regs) are SHARED by both chains; only
// chain state duplicates. One publish batch + ONE barrier per superstep
// serves TWO sim-steps -> serial-chain cost per sim-step halves vs R12.
// R12 post-mortem: VGPR=88 fit the hot set exactly (no overhead instrs);
// its 1190 cyc/step = 640 issue + ~550 uncovered chain latency. Chain B
// fills chain A's lgkmcnt shadows.
__global__ __launch_bounds__(128, 1) void plrnn_ilp2_kernel(
    const float* __restrict__ u,   // (T, N, 16)
    const float* __restrict__ z0,  // (N, 64)
    const float* __restrict__ nz,  // (T, N, 64)
    const float* __restrict__ nx,  // (T, N, 32)
    const float* __restrict__ AW,  // (64, 64)
    const float* __restrict__ Cm,  // (64, 16)
    const float* __restrict__ Bm,  // (32, 64)
    const float* __restrict__ Q,   // (64,)
    const float* __restrict__ R,   // (32,)
    float* __restrict__ zo,        // (T, N, 64)
    float* __restrict__ xo)        // (T, N, 32)
{
    const int tid  = threadIdx.x;
    const int lane = tid & 63;
    const int kh   = tid >> 6;            // k-half 0/1 (wave id in block)
    const int p    = lane & 31;           // x output row
    const int kq   = 32 * kh + ((lane >> 5) << 4);   // 16-k quarter for x
    const int sA   = __builtin_amdgcn_readfirstlane((int)(blockIdx.x * 2));
    const int sB   = sA + 1;

    __shared__ float smem[SMEM_FLOATS];

    {   // one-time stage (128 threads): AW 32/thr, C 8/thr, B 16/thr
        const int r = tid >> 1;
        const int c = (tid & 1) * 32;
        #pragma unroll
        for (int k = 0; k < 32; ++k) smem[AW_B + r * (DZ + 1) + c + k] = AW[r * DZ + c + k];
        const int cc = (tid & 1) * 8;
        #pragma unroll
        for (int k = 0; k < 8; ++k) smem[C_B + r * (DS + 1) + cc + k] = Cm[r * DS + cc + k];
        const int br = tid >> 2;
        const int bc = (tid & 3) * 16;
        #pragma unroll
        for (int k = 0; k < 16; ++k) smem[B_B + br * (DZ + 1) + bc + k] = Bm[br * DZ + bc + k];
    }
    __syncthreads();

    // per-lane weight slices -> registers (R12/R16-proven resident pattern)
    float Wrow[32];                       // W_off[lane][32kh .. 32kh+31]
    #pragma unroll
    for (int j = 0; j < 32; ++j) {
        const int k = 32 * kh + j;
        const float w = smem[AW_B + lane * (DZ + 1) + k];
        Wrow[j] = (k == lane) ? 0.f : w;  // zero diagonal (select, not index)
    }
    const float Ad = smem[AW_B + lane * (DZ + 1) + lane];
    float Crow[8];                        // C[lane][8kh .. 8kh+7]
    #pragma unroll
    for (int j = 0; j < 8; ++j) Crow[j] = smem[C_B + lane * (DS + 1) + 8 * kh + j];
    float Brow[16];                       // B[p][kq .. kq+15]
    #pragma unroll
    for (int j = 0; j < 16; ++j) Brow[j] = smem[B_B + p * (DZ + 1) + kq + j];

    const float qv = softplus_eps(Q[lane]);
    const float rv = softplus_eps(R[p]);

    __syncthreads();   // staging reads done before overlay clobbers it

    float zlA = z0[sA * DZ + lane];       // both waves: identical copies
    float zlB = z0[sB * DZ + lane];

    // uniform bases (SGPR-friendly)
    const float*  nzA = nz + sA * DZ;
    const float*  nzB = nz + sB * DZ;
    const float*  nxA = nx + sA * DX;
    const float*  nxB = nx + sB * DX;
    const float4* uA4 = (const float4*)(u + sA * DS + 8 * kh);  // wave's 8 u's
    const float4* uB4 = (const float4*)(u + sB * DS + 8 * kh);
    float* zoA = zo + sA * DZ;
    float* zoB = zo + sB * DZ;
    float* xoA = xo + sA * DX;
    float* xoB = xo + sB * DX;

    // prefetch depth 4 per sim, index-clamped (tail-safe)
    float nzpA[4], nzpB[4], nxpA[4], nxpB[4];
    float4 upA0[4], upA1[4], upB0[4], upB1[4];   // wave-uniform -> s_load
    #pragma unroll
    for (int j = 0; j < 4; ++j) {
        nzpA[j] = nzA[lane + j * SNZ];
        nzpB[j] = nzB[lane + j * SNZ];
        nxpA[j] = nxA[p + j * SNX];
        nxpB[j] = nxB[p + j * SNX];
        upA0[j] = uA4[j * SU4];  upA1[j] = uA4[j * SU4 + 1];
        upB0[j] = uB4[j * SU4];  upB1[j] = uB4[j * SU4 + 1];
    }

    for (int t0 = 0; t0 < TT; t0 += 4) {
        #pragma unroll
        for (int j = 0; j < 4; ++j) {
            const int t   = t0 + j;
            const int par = j & 1;

            const float vnzA = nzpA[j], vnzB = nzpB[j];
            const float vnxA = nxpA[j], vnxB = nxpB[j];
            const float4 uaA = upA0[j], ubA = upA1[j];
            const float4 uaB = upB0[j], ubB = upB1[j];

            // ---- phase 1: publish BOTH sims' z_t (one batch, one round-trip)
            smem[ZR_O +       lane] = zlA;
            smem[ZR_O +  64 + lane] = zlB;
            smem[RZ_O +       lane] = fmaxf(zlA, 0.f);
            smem[RZ_O +  64 + lane] = fmaxf(zlB, 0.f);
            if (kh == 0) {                       // emit z_t (pre-update)
                zoA[lane + t * SNZ] = zlA;
                zoB[lane + t * SNZ] = zlB;
            }

            // u-dots (register/SGPR operands; fill the LDS latency shadow)
            float a0 = Crow[0] * uaA.x, a1 = Crow[1] * uaA.y;
            float a2 = Crow[2] * uaA.z, a3 = Crow[3] * uaA.w;
            a0 = fmaf(Crow[4], ubA.x, a0); a1 = fmaf(Crow[5], ubA.y, a1);
            a2 = fmaf(Crow[6], ubA.z, a2); a3 = fmaf(Crow[7], ubA.w, a3);
            float e0 = Crow[0] * uaB.x, e1 = Crow[1] * uaB.y;
            float e2 = Crow[2] * uaB.z, e3 = Crow[3] * uaB.w;
            e0 = fmaf(Crow[4], ubB.x, e0); e1 = fmaf(Crow[5], ubB.y, e1);
            e2 = fmaf(Crow[6], ubB.z, e2); e3 = fmaf(Crow[7], ubB.w, e3);

            // refill prefetch (clamped; tail values loaded but unused)
            {
                int tn = t + 4; tn = (tn < TT) ? tn : (TT - 1);
                nzpA[j] = nzA[lane + tn * SNZ];
                nzpB[j] = nzB[lane + tn * SNZ];
                nxpA[j] = nxA[p + tn * SNX];
                nxpB[j] = nxB[p + tn * SNX];
                upA0[j] = uA4[tn * SU4];  upA1[j] = uA4[tn * SU4 + 1];
                upB0[j] = uB4[tn * SU4];  upB1[j] = uB4[tn * SU4 + 1];
            }

            // W-half dots: 8 broadcast ds_read_b128 per sim (interleaved A/B)
            #pragma unroll
            for (int k4 = 0; k4 < 8; ++k4) {
                const float4 zA = *(const float4*)&smem[RZ_O +      32 * kh + 4 * k4];
                const float4 zB = *(const float4*)&smem[RZ_O + 64 + 32 * kh + 4 * k4];
                a0 = fmaf(Wrow[4 * k4 + 0], zA.x, a0);
                a1 = fmaf(Wrow[4 * k4 + 1], zA.y, a1);
                a2 = fmaf(Wrow[4 * k4 + 2], zA.z, a2);
                a3 = fmaf(Wrow[4 * k4 + 3], zA.w, a3);
                e0 = fmaf(Wrow[4 * k4 + 0], zB.x, e0);
                e1 = fmaf(Wrow[4 * k4 + 1], zB.y, e1);
                e2 = fmaf(Wrow[4 * k4 + 2], zB.z, e2);
                e3 = fmaf(Wrow[4 * k4 + 3], zB.w, e3);
            }

            // x-quarter dots: 4 broadcast ds_read_b128 per sim
            float xA0 = 0.f, xA1 = 0.f, xB0 = 0.f, xB1 = 0.f;
            #pragma unroll
            for (int k4 = 0; k4 < 4; ++k4) {
                const float4 zA = *(const float4*)&smem[ZR_O +      kq + 4 * k4];
                const float4 zB = *(const float4*)&smem[ZR_O + 64 + kq + 4 * k4];
                xA0 = fmaf(Brow[4 * k4 + 0], zA.x, xA0);
                xA1 = fmaf(Brow[4 * k4 + 1], zA.y, xA1);
                xA0 = fmaf(Brow[4 * k4 + 2], zA.z, xA0);
                xA1 = fmaf(Brow[4 * k4 + 3], zA.w, xA1);
                xB0 = fmaf(Brow[4 * k4 + 0], zB.x, xB0);
                xB1 = fmaf(Brow[4 * k4 + 1], zB.y, xB1);
                xB0 = fmaf(Brow[4 * k4 + 2], zB.z, xB0);
                xB1 = fmaf(Brow[4 * k4 + 3], zB.w, xB1);
            }
            float xpA = xA0 + xA1;
            float xpB = xB0 + xB1;
            xpA += __shfl_xor(xpA, 32);   // merge the two 16-k quarters
            xpB += __shfl_xor(xpB, 32);

            const float mA = (a0 + a1) + (a2 + a3);
            const float mB = (e0 + e1) + (e2 + e3);
            smem[PM_O + par * 256 +       kh * 64 + lane] = mA;
            smem[PM_O + par * 256 + 128 + kh * 64 + lane] = mB;
            if (kh == 0 && lane < 32) {
                smem[PX_O + par * 64 +      p] = xpA;
                smem[PX_O + par * 64 + 32 + p] = xpB;
            }

            lds_barrier();   // ONE barrier per superstep (2 sim-steps)

            // ---- phase 2: combine partials (fixed order -> bit-identical)
            const float moA = smem[PM_O + par * 256 +       (1 - kh) * 64 + lane];
            const float moB = smem[PM_O + par * 256 + 128 + (1 - kh) * 64 + lane];
            const float h0A = (kh == 0) ? mA : moA;
            const float h1A = (kh == 0) ? moA : mA;
            const float h0B = (kh == 0) ? mB : moB;
            const float h1B = (kh == 0) ? moB : mB;

            if (kh == 1 && lane < 32) {          // wave1 finishes + stores x_t
                xoA[p + t * SNX] = fmaf(vnxA, rv, xpA + smem[PX_O + par * 64 + p]);
                xoB[p + t * SNX] = fmaf(vnxB, rv, xpB + smem[PX_O + par * 64 + 32 + p]);
            }

            // z_{t+1} = A_diag*z + (half0 + half1) + q*nz
            zlA = fmaf(qv, vnzA, fmaf(Ad, zlA, h0A + h1A));
            zlB = fmaf(qv, vnzB, fmaf(Ad, zlB, h0B + h1B));
        }
    }
}

extern "C" void kernel_launch(void* const* d_in, const int* in_sizes, int n_in,
                              void* d_out, int out_size, void* d_ws, size_t ws_size,
                              hipStream_t stream) {
    const float* u_  = (const float*)d_in[0];
    const float* z0_ = (const float*)d_in[1];
    const float* nz_ = (const float*)d_in[2];
    const float* nx_ = (const float*)d_in[3];
    const float* AW_ = (const float*)d_in[4];
    const float* C_  = (const float*)d_in[5];
    const float* B_  = (const float*)d_in[6];
    const float* Q_  = (const float*)d_in[7];
    const float* R_  = (const float*)d_in[8];

    float* zo = (float*)d_out;                 // (T,N,64) first
    float* xo = zo + (size_t)TT * NS * DZ;     // then (T,N,32)

    hipLaunchKernelGGL(plrnn_ilp2_kernel, dim3(NS / 2), dim3(128), 0, stream,
                       u_, z0_, nz_, nx_, AW_, C_, B_, Q_, R_, zo, xo);
}